// Round 1
// baseline (864.307 us; speedup 1.0000x reference)
//
#include <hip/hip_runtime.h>
#include <hip/hip_bf16.h>
#include <stdint.h>

// Swin windowed MHA: N=32, H=W=64, C=512, heads=16, head_dim=32, window 8x8 (E=64).
// Pipeline: conv x->bf16 ; transpose weights ; GEMM1(qkv)+scatter ; windowed attn ; GEMM2(out).
// Scratch layout: ws[0..134MB) = x_bf16 (reused as attn_out), ws[134..268MB) = V^T,
// then qkv_w^T (1.5MB), out_w^T (0.5MB). Q,K live in d_out until final GEMM overwrites it.

typedef __attribute__((ext_vector_type(4))) float  f32x4;
typedef __attribute__((ext_vector_type(4))) float  fvec4;
typedef __attribute__((ext_vector_type(8))) short  s16x8;
typedef __attribute__((ext_vector_type(8))) __bf16 bf16x8;
typedef unsigned short u16;
typedef unsigned int   u32;
typedef __attribute__((ext_vector_type(4))) u16 u16x4;

__device__ __forceinline__ u16 f2bf(float f) {
  u32 u = __builtin_bit_cast(u32, f);
  u32 r = (u + 0x7FFFu + ((u >> 16) & 1u)) >> 16;
  return (u16)r;
}

__device__ __forceinline__ f32x4 mfma16(s16x8 a, s16x8 b, f32x4 c) {
  return __builtin_amdgcn_mfma_f32_16x16x32_bf16((bf16x8)a, (bf16x8)b, c, 0, 0, 0);
}

__device__ __forceinline__ void gload16(const u16* g, u16* l) {
  __builtin_amdgcn_global_load_lds(
      (const __attribute__((address_space(1))) u32*)g,
      (__attribute__((address_space(3))) u32*)l, 16, 0, 0);
}

// ---------------- conversion kernels ----------------
__global__ void k_conv_x(const float* __restrict__ x, u16* __restrict__ xb, int n4) {
  int i = blockIdx.x * 256 + threadIdx.x;
  if (i >= n4) return;
  fvec4 v = ((const fvec4*)x)[i];
  u16x4 o;
  o.x = f2bf(v.x); o.y = f2bf(v.y); o.z = f2bf(v.z); o.w = f2bf(v.w);
  ((u16x4*)xb)[i] = o;
}

__global__ void k_transpose_w(const float* __restrict__ w, u16* __restrict__ wt, int K, int N) {
  int i = blockIdx.x * 256 + threadIdx.x;
  if (i >= K * N) return;
  int k = i / N, n = i - k * N;
  wt[n * K + k] = f2bf(w[i]);
}

// ---------------- GEMM (128x128 tile, BK=32, K=512 fixed) ----------------
// MODE 0: qkv projection, scatter epilogue to Q/K/VT (bf16) with qkv_b.
// MODE 1: out projection, write fp32 Out with out_b.
template <int MODE>
__global__ __launch_bounds__(256, 2)
void k_gemm(const u16* __restrict__ A, const u16* __restrict__ B,
            const float* __restrict__ bias,
            u16* __restrict__ Qb, u16* __restrict__ Kb, u16* __restrict__ VT,
            float* __restrict__ Out) {
  __shared__ u16 ldsA[128 * 32];
  __shared__ u16 ldsB[128 * 32];
  const int tid = threadIdx.x;
  const int wid = tid >> 6, lane = tid & 63;
  const int quad = lane >> 4, col_l = lane & 15;
  const int wr = wid >> 1, wc = wid & 1;
  const int m0 = blockIdx.x * 128, n0 = blockIdx.y * 128;
  const int sr = tid >> 2, sk = (tid & 3) * 8;

  const u16* Ab = A + (size_t)(m0 + sr) * 512 + sk;
  const u16* Bb = B + (size_t)(n0 + sr) * 512 + sk;
  u16* la = &ldsA[sr * 32 + sk];
  u16* lb = &ldsB[sr * 32 + sk];

  f32x4 acc[4][4] = {};

  for (int kt = 0; kt < 512; kt += 32) {
    __syncthreads();
    gload16(Ab + kt, la);
    gload16(Ab + kt + 64 * 512, la + 64 * 32);
    gload16(Bb + kt, lb);
    gload16(Bb + kt + 64 * 512, lb + 64 * 32);
    __syncthreads();
    s16x8 af[4], bf[4];
#pragma unroll
    for (int r = 0; r < 4; ++r)
      af[r] = *(const s16x8*)&ldsA[(wr * 64 + r * 16 + col_l) * 32 + quad * 8];
#pragma unroll
    for (int c = 0; c < 4; ++c)
      bf[c] = *(const s16x8*)&ldsB[(wc * 64 + c * 16 + col_l) * 32 + quad * 8];
#pragma unroll
    for (int r = 0; r < 4; ++r)
#pragma unroll
      for (int c = 0; c < 4; ++c)
        acc[r][c] = mfma16(af[r], bf[c], acc[r][c]);
  }

#pragma unroll
  for (int r = 0; r < 4; ++r) {
#pragma unroll
    for (int c = 0; c < 4; ++c) {
      const int cc = n0 + wc * 64 + c * 16 + col_l;
      const float bv = bias[cc];
      f32x4 v = acc[r][c];
      if (MODE == 0) {
        const int which = cc >> 9, rem = cc & 511, head = rem >> 5, d = rem & 31;
#pragma unroll
        for (int i = 0; i < 4; ++i) {
          const int m = m0 + wr * 64 + r * 16 + quad * 4 + i;
          const int nimg = m >> 12, h = (m >> 6) & 63, w = m & 63;
          const int win = nimg * 64 + (h >> 3) * 8 + (w >> 3);
          const int e = (h & 7) * 8 + (w & 7);
          const int base = win * 16 + head;
          const u16 ov = f2bf(v[i] + bv);
          if (which == 0)      Qb[(base * 64 + e) * 32 + d] = ov;
          else if (which == 1) Kb[(base * 64 + e) * 32 + d] = ov;
          else                 VT[(base * 32 + d) * 64 + e] = ov;
        }
      } else {
#pragma unroll
        for (int i = 0; i < 4; ++i) {
          const int m = m0 + wr * 64 + r * 16 + quad * 4 + i;
          Out[(size_t)m * 512 + cc] = v[i] + bv;
        }
      }
    }
  }
}

// ---------------- windowed attention ----------------
// 1 wave per (window, head). S = Q K^T (16 mfma, K=32), softmax in-register,
// P staged through XOR-swizzled LDS, O = P V (16 mfma over K=64), deferred 1/sum.
__global__ __launch_bounds__(256, 2)
void k_attn(const u16* __restrict__ Q, const u16* __restrict__ K,
            const u16* __restrict__ VT, const float* __restrict__ mask,
            const float* __restrict__ btab, u16* __restrict__ AO) {
  __shared__ u16 plds[4 * 4096];
  const int tid = threadIdx.x;
  const int wid = tid >> 6, lane = tid & 63;
  const int quad = lane >> 4, col_l = lane & 15;
  const int bid = blockIdx.x;
  const int win = bid >> 2;
  const int head = ((bid & 3) << 2) | wid;
  const int nimg = win >> 6, a = (win >> 3) & 7, b = win & 7;
  const size_t wh = (size_t)(win * 16 + head);
  const u16* qb  = Q  + wh * 2048;
  const u16* kb  = K  + wh * 2048;
  const u16* vtb = VT + wh * 2048;

  s16x8 aq[4], bk[4];
#pragma unroll
  for (int t = 0; t < 4; ++t) {
    aq[t] = *(const s16x8*)&qb[(t * 16 + col_l) * 32 + quad * 8];
    bk[t] = *(const s16x8*)&kb[(t * 16 + col_l) * 32 + quad * 8];
  }
  f32x4 s[4][4] = {};
#pragma unroll
  for (int r = 0; r < 4; ++r)
#pragma unroll
    for (int c = 0; c < 4; ++c)
      s[r][c] = mfma16(aq[r], bk[c], s[r][c]);

  const float scale = 0.17677669529663687f;  // 1/sqrt(32)
  const float* mrow = mask + (size_t)(a * 8 + b) * 4096;
#pragma unroll
  for (int r = 0; r < 4; ++r)
#pragma unroll
    for (int c = 0; c < 4; ++c)
#pragma unroll
      for (int i = 0; i < 4; ++i) {
        const int row = r * 16 + quad * 4 + i, col = c * 16 + col_l;
        const int dh = (row >> 3) - (col >> 3) + 7;
        const int dw = (row & 7) - (col & 7) + 7;
        s[r][c][i] = s[r][c][i] * scale + btab[(dh * 15 + dw) * 16 + head] +
                     mrow[row * 64 + col];
      }

  float rinv[4][4];
#pragma unroll
  for (int r = 0; r < 4; ++r) {
#pragma unroll
    for (int i = 0; i < 4; ++i) {
      float mx = fmaxf(fmaxf(s[r][0][i], s[r][1][i]), fmaxf(s[r][2][i], s[r][3][i]));
      mx = fmaxf(mx, __shfl_xor(mx, 1));
      mx = fmaxf(mx, __shfl_xor(mx, 2));
      mx = fmaxf(mx, __shfl_xor(mx, 4));
      mx = fmaxf(mx, __shfl_xor(mx, 8));
      float sum = 0.f;
#pragma unroll
      for (int c = 0; c < 4; ++c) {
        float p = __expf(s[r][c][i] - mx);
        s[r][c][i] = p;
        sum += p;
      }
      sum += __shfl_xor(sum, 1);
      sum += __shfl_xor(sum, 2);
      sum += __shfl_xor(sum, 4);
      sum += __shfl_xor(sum, 8);
      rinv[r][i] = 1.0f / sum;
    }
  }

  u16* pl = &plds[wid * 4096];
#pragma unroll
  for (int r = 0; r < 4; ++r)
#pragma unroll
    for (int c = 0; c < 4; ++c)
#pragma unroll
      for (int i = 0; i < 4; ++i) {
        const int row = r * 16 + quad * 4 + i, col = c * 16 + col_l;
        const int off = (row * 128 + col * 2) ^ ((row & 7) << 4);
        *(u16*)((char*)pl + off) = f2bf(s[r][c][i]);
      }
  __syncthreads();

  s16x8 bv[2][2];
#pragma unroll
  for (int c2 = 0; c2 < 2; ++c2)
#pragma unroll
    for (int ks = 0; ks < 2; ++ks)
      bv[c2][ks] = *(const s16x8*)&vtb[(c2 * 16 + col_l) * 64 + ks * 32 + quad * 8];

  f32x4 o[4][2] = {};
#pragma unroll
  for (int r = 0; r < 4; ++r) {
#pragma unroll
    for (int ks = 0; ks < 2; ++ks) {
      const int row = r * 16 + col_l;
      const int off = (row * 128 + (ks * 32 + quad * 8) * 2) ^ ((row & 7) << 4);
      s16x8 pa = *(const s16x8*)((char*)pl + off);
#pragma unroll
      for (int c2 = 0; c2 < 2; ++c2)
        o[r][c2] = mfma16(pa, bv[c2][ks], o[r][c2]);
    }
  }

#pragma unroll
  for (int r = 0; r < 4; ++r) {
#pragma unroll
    for (int i = 0; i < 4; ++i) {
      const int row = r * 16 + quad * 4 + i;
      const int h = a * 8 + (row >> 3), w = b * 8 + (row & 7);
      const size_t m = (size_t)nimg * 4096 + (size_t)h * 64 + w;
      const float inv = rinv[r][i];
#pragma unroll
      for (int c2 = 0; c2 < 2; ++c2)
        AO[m * 512 + head * 32 + c2 * 16 + col_l] = f2bf(o[r][c2][i] * inv);
    }
  }
}

// ---------------- launch ----------------
extern "C" void kernel_launch(void* const* d_in, const int* in_sizes, int n_in,
                              void* d_out, int out_size, void* d_ws, size_t ws_size,
                              hipStream_t stream) {
  const float* x     = (const float*)d_in[0];
  const float* mask  = (const float*)d_in[1];
  const float* qkv_w = (const float*)d_in[2];
  const float* qkv_b = (const float*)d_in[3];
  const float* out_w = (const float*)d_in[4];
  const float* out_b = (const float*)d_in[5];
  const float* btab  = (const float*)d_in[6];

  char* ws = (char*)d_ws;
  u16* xb    = (u16*)ws;                        // 134,217,728 B (x bf16, reused as attn_out)
  u16* vt    = (u16*)(ws + 134217728);          // 134,217,728 B (V^T)
  u16* wqkvT = (u16*)(ws + 268435456);          // 1,572,864 B
  u16* woT   = (u16*)(ws + 270008320);          // 524,288 B

  u16* Qb = (u16*)d_out;                        // 134,217,728 B
  u16* Kb = (u16*)d_out + 67108864;             // 134,217,728 B

  k_conv_x<<<65536, 256, 0, stream>>>(x, xb, 16777216);
  k_transpose_w<<<3072, 256, 0, stream>>>(qkv_w, wqkvT, 512, 1536);
  k_transpose_w<<<1024, 256, 0, stream>>>(out_w, woT, 512, 512);
  k_gemm<0><<<dim3(1024, 12), 256, 0, stream>>>(xb, wqkvT, qkv_b, Qb, Kb, vt, nullptr);
  k_attn<<<8192, 256, 0, stream>>>(Qb, Kb, vt, mask, btab, xb);
  k_gemm<1><<<dim3(1024, 4), 256, 0, stream>>>(xb, woT, out_b, nullptr, nullptr, nullptr,
                                               (float*)d_out);
}